// Round 4
// baseline (1188.523 us; speedup 1.0000x reference)
//
#include <hip/hip_runtime.h>
#include <math.h>

#define N_NODES 50000
#define N_EDGES 800000
#define N_GRAPHS 512
#define D 64
#define D_CLS 128
#define BNODES 256                      // dst nodes per bucket
#define NBUK 196                        // cdiv(N_NODES, BNODES)
#define PART_TILE 4096                  // edges per k_part block (256 thr x 16)

static inline int cdiv(int a, int b) { return (a + b - 1) / b; }

// ---------- degree histogram (per node) ----------

__global__ void k_hist(const int* __restrict__ dst, int* __restrict__ cnt) {
    int e = blockIdx.x * blockDim.x + threadIdx.x;
    if (e < N_EDGES) atomicAdd(&cnt[dst[e]], 1);
}

// one wave per bucket: bucket edge-count + per-node dis = 1/sqrt(deg+1)
__global__ void k_bsum(const int* __restrict__ cnt, int* __restrict__ bcnt,
                       float* __restrict__ dis) {
    int b = blockIdx.x;
    int lane = threadIdx.x;            // 64 threads
    int n0 = b << 8;
    int s = 0;
    #pragma unroll
    for (int k = 0; k < 4; k++) {
        int n = n0 + lane + k * 64;
        if (n < N_NODES) {
            int c = cnt[n];
            s += c;
            dis[n] = 1.0f / sqrtf((float)c + 1.0f);
        }
    }
    #pragma unroll
    for (int m = 1; m < 64; m <<= 1) s += __shfl_xor(s, m, 64);
    if (lane == 0) bcnt[b] = s;
}

// single-block exclusive scan of bucket counts -> bbase, btail
__global__ void k_bscan(const int* __restrict__ bcnt, int* __restrict__ bbase,
                        int* __restrict__ btail) {
    __shared__ int sh[256];
    int t = threadIdx.x;
    int v = (t < NBUK) ? bcnt[t] : 0;
    sh[t] = v;
    __syncthreads();
    for (int off = 1; off < 256; off <<= 1) {
        int x = (t >= off) ? sh[t - off] : 0;
        __syncthreads();
        sh[t] += x;
        __syncthreads();
    }
    if (t < NBUK) { bbase[t] = sh[t] - v; btail[t] = sh[t] - v; }
}

// ---------- partition edges into buckets (LDS histogram; dense-ish writes) ----

__global__ __launch_bounds__(256) void k_part(
        const int* __restrict__ src, const int* __restrict__ dst,
        int* __restrict__ btail, int* __restrict__ ebuf) {
    __shared__ int lcnt[NBUK];
    __shared__ int lbase[NBUK];
    int t = threadIdx.x;
    for (int i = t; i < NBUK; i += 256) lcnt[i] = 0;
    __syncthreads();

    int e0 = blockIdx.x * PART_TILE + t;
    int ent[16];
    int br[16];
    #pragma unroll
    for (int k = 0; k < 16; k++) {
        int e = e0 + k * 256;
        if (e < N_EDGES) {
            int d = dst[e];
            int b = d >> 8;
            int r = atomicAdd(&lcnt[b], 1);
            ent[k] = src[e] | ((d & 255) << 16);   // src(16b) | dlocal(8b)<<16
            br[k] = (b << 16) | r;                  // r < 4096 fits 16b
        } else {
            br[k] = -1;
        }
    }
    __syncthreads();
    for (int i = t; i < NBUK; i += 256) {
        int c = lcnt[i];
        lbase[i] = c ? atomicAdd(&btail[i], c) : 0;   // 1 atomic per (block,bucket)
    }
    __syncthreads();
    #pragma unroll
    for (int k = 0; k < 16; k++) {
        if (br[k] >= 0) {
            int b = br[k] >> 16, r = br[k] & 0xFFFF;
            ebuf[lbase[b] + r] = ent[k];
        }
    }
}

// ---------- GEMM (X @ W) with dis-row-scaling fused: G = dis ⊙ (X @ W) ----------

#define XS_STRIDE 68   // 64 + 4 pad, keeps 16B alignment for float4 LDS ops

__global__ __launch_bounds__(256) void k_gemm_scale(
        const float* __restrict__ X, const float* __restrict__ W,
        const float* __restrict__ dis, float* __restrict__ G) {
    __shared__ float Xs[64 * XS_STRIDE];
    __shared__ float Ws[64 * 64];
    int n0 = blockIdx.x * 64;
    int t = threadIdx.x;

    {
        int base = t * 16;
        const float4* wsrc = (const float4*)(W + base);
        float4* wdst = (float4*)(Ws + base);
        wdst[0] = wsrc[0]; wdst[1] = wsrc[1]; wdst[2] = wsrc[2]; wdst[3] = wsrc[3];
    }
    {
        int row = t >> 2;
        int c0 = (t & 3) * 16;
        int grow = n0 + row;
        float4* xd = (float4*)(Xs + row * XS_STRIDE + c0);
        if (grow < N_NODES) {
            const float4* xp = (const float4*)(X + (size_t)grow * D + c0);
            xd[0] = xp[0]; xd[1] = xp[1]; xd[2] = xp[2]; xd[3] = xp[3];
        } else {
            float4 z = {0.f, 0.f, 0.f, 0.f};
            xd[0] = z; xd[1] = z; xd[2] = z; xd[3] = z;
        }
    }
    __syncthreads();

    int tc = t & 15, tr = t >> 4;
    int r0 = tr * 4, c0 = tc * 4;
    float acc[4][4] = {};
    #pragma unroll 4
    for (int k = 0; k < 64; k++) {
        float4 wv = *(const float4*)&Ws[k * 64 + c0];
        #pragma unroll
        for (int i = 0; i < 4; i++) {
            float xv = Xs[(r0 + i) * XS_STRIDE + k];
            acc[i][0] = fmaf(xv, wv.x, acc[i][0]);
            acc[i][1] = fmaf(xv, wv.y, acc[i][1]);
            acc[i][2] = fmaf(xv, wv.z, acc[i][2]);
            acc[i][3] = fmaf(xv, wv.w, acc[i][3]);
        }
    }
    #pragma unroll
    for (int i = 0; i < 4; i++) {
        int grow = n0 + r0 + i;
        if (grow < N_NODES) {
            float dsc = dis[grow];
            float4 o;
            o.x = acc[i][0] * dsc; o.y = acc[i][1] * dsc;
            o.z = acc[i][2] * dsc; o.w = acc[i][3] * dsc;
            *(float4*)&G[(size_t)grow * D + c0] = o;
        }
    }
}

// ---------- aggregation via per-bucket LDS accumulators ----------
// block = bucket (256 dst nodes), LDS acc[256][64] = 64KB. 8 waves stream the
// bucket's contiguous edge slice; each 16-lane group handles one edge (float4
// per lane), 4 edges in flight per wave-iteration; LDS float atomics
// accumulate. Epilogue: Out = dis*(acc + G_self) + bias (dense).

__global__ __launch_bounds__(512) void k_agg_lds(
        const float* __restrict__ G, const int* __restrict__ ebuf,
        const int* __restrict__ bbase, const int* __restrict__ bcnt,
        const float* __restrict__ dis, const float* __restrict__ bias,
        float* __restrict__ Out) {
    __shared__ float acc[BNODES * D];   // 64 KB
    int t = threadIdx.x;
    int b = blockIdx.x;

    float4 z = {0.f, 0.f, 0.f, 0.f};
    for (int i = t; i < BNODES * D / 4; i += 512) ((float4*)acc)[i] = z;
    __syncthreads();

    int start = bbase[b];
    int cntE  = bcnt[b];
    int lane = t & 63, w = t >> 6;      // 8 waves
    int es = lane >> 4;                 // edge slot 0..3
    int fg4 = (lane & 15) * 4;          // feature float4 offset

    for (int i0 = w * 16 + es; i0 < cntE; i0 += 128) {
        int i1 = i0 + 4, i2 = i0 + 8, i3 = i0 + 12;
        int E0 = ebuf[start + i0];
        int E1 = ebuf[start + (i1 < cntE ? i1 : i0)];
        int E2 = ebuf[start + (i2 < cntE ? i2 : i0)];
        int E3 = ebuf[start + (i3 < cntE ? i3 : i0)];
        float f1 = (i1 < cntE) ? 1.f : 0.f;
        float f2 = (i2 < cntE) ? 1.f : 0.f;
        float f3 = (i3 < cntE) ? 1.f : 0.f;
        int s0 = E0 & 0xFFFF, d0 = (E0 >> 16) & 0xFF;
        int s1 = E1 & 0xFFFF, d1 = (E1 >> 16) & 0xFF;
        int s2 = E2 & 0xFFFF, d2 = (E2 >> 16) & 0xFF;
        int s3 = E3 & 0xFFFF, d3 = (E3 >> 16) & 0xFF;
        float4 g0 = *(const float4*)(G + (size_t)s0 * D + fg4);
        float4 g1 = *(const float4*)(G + (size_t)s1 * D + fg4);
        float4 g2 = *(const float4*)(G + (size_t)s2 * D + fg4);
        float4 g3 = *(const float4*)(G + (size_t)s3 * D + fg4);
        float* a0 = acc + d0 * D + fg4;
        float* a1 = acc + d1 * D + fg4;
        float* a2 = acc + d2 * D + fg4;
        float* a3 = acc + d3 * D + fg4;
        atomicAdd(a0 + 0, g0.x); atomicAdd(a0 + 1, g0.y);
        atomicAdd(a0 + 2, g0.z); atomicAdd(a0 + 3, g0.w);
        atomicAdd(a1 + 0, g1.x * f1); atomicAdd(a1 + 1, g1.y * f1);
        atomicAdd(a1 + 2, g1.z * f1); atomicAdd(a1 + 3, g1.w * f1);
        atomicAdd(a2 + 0, g2.x * f2); atomicAdd(a2 + 1, g2.y * f2);
        atomicAdd(a2 + 2, g2.z * f2); atomicAdd(a2 + 3, g2.w * f2);
        atomicAdd(a3 + 0, g3.x * f3); atomicAdd(a3 + 1, g3.y * f3);
        atomicAdd(a3 + 2, g3.z * f3); atomicAdd(a3 + 3, g3.w * f3);
    }
    __syncthreads();

    // epilogue: 32 node-slots (8 waves x 4 es), 16 feature lanes each
    for (int nl = w * 4 + es; nl < BNODES; nl += 32) {
        int n = (b << 8) + nl;
        if (n < N_NODES) {
            float4 a = *(float4*)&acc[nl * D + fg4];
            float4 g = *(const float4*)(G + (size_t)n * D + fg4);
            float4 bv = *(const float4*)(bias + fg4);
            float dsc = dis[n];
            float4 o;
            o.x = fmaf(dsc, a.x + g.x, bv.x);
            o.y = fmaf(dsc, a.y + g.y, bv.y);
            o.z = fmaf(dsc, a.z + g.z, bv.z);
            o.w = fmaf(dsc, a.w + g.w, bv.w);
            *(float4*)(Out + (size_t)n * D + fg4) = o;
        }
    }
}

// ---------- pooling ----------

__global__ void k_bounds(const int* __restrict__ batch, int* __restrict__ start) {
    int g = blockIdx.x * blockDim.x + threadIdx.x;
    if (g <= N_GRAPHS) {
        int lo = 0, hi = N_NODES;
        while (lo < hi) {
            int mid = (lo + hi) >> 1;
            if (batch[mid] < g) lo = mid + 1; else hi = mid;
        }
        start[g] = lo;
    }
}

__global__ __launch_bounds__(256) void k_pool(
        const float* __restrict__ H, const int* __restrict__ start,
        float* __restrict__ P) {
    int g = blockIdx.x * 4 + (threadIdx.x >> 6);
    if (g >= N_GRAPHS) return;
    int lane = threadIdx.x & 63;
    int es  = lane >> 4;
    int fg4 = (lane & 15) * 4;
    int s = start[g], e = start[g + 1];
    float4 acc = {0.f, 0.f, 0.f, 0.f};
    for (int r = s + es; r < e; r += 4) {
        float4 h = *(const float4*)(H + (size_t)r * D + fg4);
        acc.x += h.x; acc.y += h.y; acc.z += h.z; acc.w += h.w;
    }
    #pragma unroll
    for (int m = 16; m < 64; m <<= 1) {
        acc.x += __shfl_xor(acc.x, m, 64);
        acc.y += __shfl_xor(acc.y, m, 64);
        acc.z += __shfl_xor(acc.z, m, 64);
        acc.w += __shfl_xor(acc.w, m, 64);
    }
    int cntr = e - s;
    float inv = 1.0f / (float)(cntr > 0 ? cntr : 1);
    if (es == 0) {
        float4 o;
        o.x = acc.x * inv; o.y = acc.y * inv; o.z = acc.z * inv; o.w = acc.w * inv;
        *(float4*)(P + g * D + fg4) = o;
    }
}

// ---------- classifier MLP ----------

__global__ __launch_bounds__(128) void k_mlp(
        const float* __restrict__ P,
        const float* __restrict__ w1, const float* __restrict__ b1,
        const float* __restrict__ w2, const float* __restrict__ b2,
        const float* __restrict__ fcw, const float* __restrict__ fcb,
        float* __restrict__ out) {
    __shared__ float ps[64];
    __shared__ float red[128];
    int g = blockIdx.x, t = threadIdx.x;
    if (t < 64) ps[t] = P[g * D + t];
    __syncthreads();
    float acc = b1[t];
    #pragma unroll
    for (int k = 0; k < 64; k++) acc = fmaf(ps[k], w1[k * D_CLS + t], acc);
    red[t] = acc * w2[t];
    __syncthreads();
    for (int s2 = 64; s2 > 0; s2 >>= 1) {
        if (t < s2) red[t] += red[t + s2];
        __syncthreads();
    }
    if (t == 0) {
        float o = red[0] + b2[0];
        o = fmaf(o, fcw[0], fcb[0]);
        out[g] = (o >= 0.f) ? o : 0.01f * o;
    }
}

// ---------- launch ----------

extern "C" void kernel_launch(void* const* d_in, const int* in_sizes, int n_in,
                              void* d_out, int out_size, void* d_ws, size_t ws_size,
                              hipStream_t stream) {
    const float* x   = (const float*)d_in[0];
    const float* W0  = (const float*)d_in[1];
    const float* b0  = (const float*)d_in[2];
    const float* W1  = (const float*)d_in[3];
    const float* b1  = (const float*)d_in[4];
    const float* W2  = (const float*)d_in[5];
    const float* b2  = (const float*)d_in[6];
    const float* l1w = (const float*)d_in[7];
    const float* l1b = (const float*)d_in[8];
    const float* l2w = (const float*)d_in[9];
    const float* l2b = (const float*)d_in[10];
    const float* fcw = (const float*)d_in[11];
    const float* fcb = (const float*)d_in[12];
    const int* eidx  = (const int*)d_in[13];
    const int* batch = (const int*)d_in[14];
    const int* src = eidx;
    const int* dst = eidx + N_EDGES;

    char* ws = (char*)d_ws;
    size_t off = 0;
    auto alloc = [&](size_t bytes) -> void* {
        off = (off + 255) & ~(size_t)255;
        void* p = ws + off;
        off += bytes;
        return p;
    };

    int*   cnt    = (int*)  alloc(N_NODES * sizeof(int));
    int*   bcnt   = (int*)  alloc(NBUK * sizeof(int));
    int*   bbase  = (int*)  alloc(NBUK * sizeof(int));
    int*   btail  = (int*)  alloc(NBUK * sizeof(int));
    int*   ebuf   = (int*)  alloc(N_EDGES * sizeof(int));
    float* dis    = (float*)alloc(N_NODES * sizeof(float));
    int*   start  = (int*)  alloc((N_GRAPHS + 1) * sizeof(int));
    float* bufA   = (float*)alloc((size_t)N_NODES * D * sizeof(float));
    float* bufB   = (float*)alloc((size_t)N_NODES * D * sizeof(float));
    float* bufC   = (float*)alloc((size_t)N_NODES * D * sizeof(float));
    float* pooled = (float*)alloc((size_t)N_GRAPHS * D * sizeof(float));

    const int nbE = cdiv(N_EDGES, 256);   // 3125

    hipMemsetAsync(cnt, 0, N_NODES * sizeof(int), stream);

    k_hist<<<nbE, 256, 0, stream>>>(dst, cnt);
    k_bsum<<<NBUK, 64, 0, stream>>>(cnt, bcnt, dis);
    k_bscan<<<1, 256, 0, stream>>>(bcnt, bbase, btail);
    k_part<<<cdiv(N_EDGES, PART_TILE), 256, 0, stream>>>(src, dst, btail, ebuf);

    const int nbGemm = cdiv(N_NODES, 64);    // 782

    // layer 0: x -> B
    k_gemm_scale<<<nbGemm, 256, 0, stream>>>(x, W0, dis, bufA);
    k_agg_lds<<<NBUK, 512, 0, stream>>>(bufA, ebuf, bbase, bcnt, dis, b0, bufB);
    // layer 1: B -> C
    k_gemm_scale<<<nbGemm, 256, 0, stream>>>(bufB, W1, dis, bufA);
    k_agg_lds<<<NBUK, 512, 0, stream>>>(bufA, ebuf, bbase, bcnt, dis, b1, bufC);
    // layer 2: C -> B
    k_gemm_scale<<<nbGemm, 256, 0, stream>>>(bufC, W2, dis, bufA);
    k_agg_lds<<<NBUK, 512, 0, stream>>>(bufA, ebuf, bbase, bcnt, dis, b2, bufB);

    k_bounds<<<cdiv(N_GRAPHS + 1, 256), 256, 0, stream>>>(batch, start);
    k_pool<<<cdiv(N_GRAPHS, 4), 256, 0, stream>>>(bufB, start, pooled);
    k_mlp<<<N_GRAPHS, 128, 0, stream>>>(pooled, l1w, l1b, l2w, l2b, fcw, fcb,
                                        (float*)d_out);
}

// Round 5
// 238.563 us; speedup vs baseline: 4.9820x; 4.9820x over previous
//
#include <hip/hip_runtime.h>
#include <math.h>

#define N_NODES 50000
#define N_EDGES 800000
#define N_GRAPHS 512
#define D 64
#define D_CLS 128
#define BNODES 128                       // dst nodes per bucket
#define NBUK 391                         // cdiv(N_NODES, BNODES)
#define PART_TILE 4096                   // edges per k_part block (256 thr x 16)

static inline int cdiv(int a, int b) { return (a + b - 1) / b; }

// ---------- degree histogram (per node) ----------

__global__ void k_hist(const int* __restrict__ dst, int* __restrict__ cnt) {
    int e = blockIdx.x * blockDim.x + threadIdx.x;
    if (e < N_EDGES) atomicAdd(&cnt[dst[e]], 1);
}

__global__ void k_dis(const int* __restrict__ cnt, float* __restrict__ dis) {
    int i = blockIdx.x * blockDim.x + threadIdx.x;
    if (i < N_NODES) dis[i] = 1.0f / sqrtf((float)cnt[i] + 1.0f);
}

// ---------- row_ptr scan (196 blocks of 256) ----------

__global__ void k_scan1(const int* __restrict__ cnt, int* __restrict__ bsum) {
    __shared__ int s[256];
    int i = blockIdx.x * 256 + threadIdx.x;
    s[threadIdx.x] = (i < N_NODES) ? cnt[i] : 0;
    __syncthreads();
    for (int off = 128; off > 0; off >>= 1) {
        if (threadIdx.x < off) s[threadIdx.x] += s[threadIdx.x + off];
        __syncthreads();
    }
    if (threadIdx.x == 0) bsum[blockIdx.x] = s[0];
}

__global__ void k_scan2(int* bsum, int nb) {
    __shared__ int s[256];
    int t = threadIdx.x;
    int v = (t < nb) ? bsum[t] : 0;
    s[t] = v;
    __syncthreads();
    for (int off = 1; off < 256; off <<= 1) {
        int x = (t >= off) ? s[t - off] : 0;
        __syncthreads();
        s[t] += x;
        __syncthreads();
    }
    if (t < nb) bsum[t] = s[t] - v;
}

__global__ void k_scan3(const int* __restrict__ cnt, const int* __restrict__ bsum,
                        int* __restrict__ row_ptr) {
    __shared__ int s[256];
    int i = blockIdx.x * 256 + threadIdx.x;
    int v = (i < N_NODES) ? cnt[i] : 0;
    s[threadIdx.x] = v;
    __syncthreads();
    for (int off = 1; off < 256; off <<= 1) {
        int x = (threadIdx.x >= off) ? s[threadIdx.x - off] : 0;
        __syncthreads();
        s[threadIdx.x] += x;
        __syncthreads();
    }
    if (i < N_NODES) row_ptr[i] = bsum[blockIdx.x] + s[threadIdx.x] - v;
    if (i == 0) row_ptr[N_NODES] = N_EDGES;
}

__global__ void k_binit(const int* __restrict__ row_ptr, int* __restrict__ btail) {
    int b = blockIdx.x * blockDim.x + threadIdx.x;
    if (b < NBUK) btail[b] = row_ptr[b * BNODES];
}

// ---------- partition edges into buckets (LDS histogram, 1 atomic/(blk,buk)) ----

__global__ __launch_bounds__(256) void k_part(
        const int* __restrict__ src, const int* __restrict__ dst,
        int* __restrict__ btail, int* __restrict__ ebuf) {
    __shared__ int lcnt[NBUK];
    __shared__ int lbase[NBUK];
    int t = threadIdx.x;
    for (int i = t; i < NBUK; i += 256) lcnt[i] = 0;
    __syncthreads();

    int e0 = blockIdx.x * PART_TILE + t;
    int ent[16];
    int br[16];
    #pragma unroll
    for (int k = 0; k < 16; k++) {
        int e = e0 + k * 256;
        if (e < N_EDGES) {
            int d = dst[e];
            int b = d / BNODES;
            int r = atomicAdd(&lcnt[b], 1);
            ent[k] = src[e] | ((d & (BNODES - 1)) << 16);  // src(16b)|dlocal(7b)
            br[k] = (b << 16) | r;                          // r < 4096
        } else {
            br[k] = -1;
        }
    }
    __syncthreads();
    for (int i = t; i < NBUK; i += 256) {
        int c = lcnt[i];
        lbase[i] = c ? atomicAdd(&btail[i], c) : 0;
    }
    __syncthreads();
    #pragma unroll
    for (int k = 0; k < 16; k++) {
        if (br[k] >= 0) {
            int b = br[k] >> 16, r = br[k] & 0xFFFF;
            ebuf[lbase[b] + r] = ent[k];
        }
    }
}

// ---------- exact CSR placement; writes confined to ~8KB bucket region ----------

__global__ __launch_bounds__(256) void k_place(
        const int* __restrict__ ebuf, const int* __restrict__ row_ptr,
        int* __restrict__ cnt, int* __restrict__ col) {
    int b = blockIdx.x;
    int n0 = b * BNODES;
    int nhi = n0 + BNODES;
    if (nhi > N_NODES) nhi = N_NODES;
    int s = row_ptr[n0];
    int e = row_ptr[nhi];
    for (int i = s + threadIdx.x; i < e; i += 256) {
        int v = ebuf[i];
        int d = n0 | (v >> 16);
        int pos = row_ptr[d] + atomicSub(&cnt[d], 1) - 1;
        col[pos] = v & 0xFFFF;
    }
}

// ---------- GEMM (X @ W) with dis-row-scaling fused: G = dis ⊙ (X @ W) ----------

#define XS_STRIDE 68   // 64 + 4 pad, keeps 16B alignment for float4 LDS ops

__global__ __launch_bounds__(256) void k_gemm_scale(
        const float* __restrict__ X, const float* __restrict__ W,
        const float* __restrict__ dis, float* __restrict__ G) {
    __shared__ float Xs[64 * XS_STRIDE];
    __shared__ float Ws[64 * 64];
    int n0 = blockIdx.x * 64;
    int t = threadIdx.x;

    {
        int base = t * 16;
        const float4* wsrc = (const float4*)(W + base);
        float4* wdst = (float4*)(Ws + base);
        wdst[0] = wsrc[0]; wdst[1] = wsrc[1]; wdst[2] = wsrc[2]; wdst[3] = wsrc[3];
    }
    {
        int row = t >> 2;
        int c0 = (t & 3) * 16;
        int grow = n0 + row;
        float4* xd = (float4*)(Xs + row * XS_STRIDE + c0);
        if (grow < N_NODES) {
            const float4* xp = (const float4*)(X + (size_t)grow * D + c0);
            xd[0] = xp[0]; xd[1] = xp[1]; xd[2] = xp[2]; xd[3] = xp[3];
        } else {
            float4 z = {0.f, 0.f, 0.f, 0.f};
            xd[0] = z; xd[1] = z; xd[2] = z; xd[3] = z;
        }
    }
    __syncthreads();

    int tc = t & 15, tr = t >> 4;
    int r0 = tr * 4, c0 = tc * 4;
    float acc[4][4] = {};
    #pragma unroll 4
    for (int k = 0; k < 64; k++) {
        float4 wv = *(const float4*)&Ws[k * 64 + c0];
        #pragma unroll
        for (int i = 0; i < 4; i++) {
            float xv = Xs[(r0 + i) * XS_STRIDE + k];
            acc[i][0] = fmaf(xv, wv.x, acc[i][0]);
            acc[i][1] = fmaf(xv, wv.y, acc[i][1]);
            acc[i][2] = fmaf(xv, wv.z, acc[i][2]);
            acc[i][3] = fmaf(xv, wv.w, acc[i][3]);
        }
    }
    #pragma unroll
    for (int i = 0; i < 4; i++) {
        int grow = n0 + r0 + i;
        if (grow < N_NODES) {
            float dsc = dis[grow];
            float4 o;
            o.x = acc[i][0] * dsc; o.y = acc[i][1] * dsc;
            o.z = acc[i][2] * dsc; o.w = acc[i][3] * dsc;
            *(float4*)&G[(size_t)grow * D + c0] = o;
        }
    }
}

// ---------- aggregation: Out_n = dis_n * (G_n + sum_{src in in(n)} G_src) + b ----
// wave = node; 4 edge-slots x 16 feature-lanes; 4 clamped+predicated gathers per
// slot-iteration -> 16 rows in flight per wave.

__global__ __launch_bounds__(256) void k_agg(
        const float* __restrict__ G, const int* __restrict__ row_ptr,
        const int* __restrict__ col, const float* __restrict__ dis,
        const float* __restrict__ bias, float* __restrict__ Out) {
    int n = blockIdx.x * 4 + (threadIdx.x >> 6);
    if (n >= N_NODES) return;
    int lane = threadIdx.x & 63;
    int es  = lane >> 4;          // edge slot 0..3
    int fg4 = (lane & 15) * 4;    // feature offset

    int s = row_ptr[n], e = row_ptr[n + 1];
    float4 acc = {0.f, 0.f, 0.f, 0.f};

    for (int i = s + es; i < e; i += 16) {
        int i1 = i + 4, i2 = i + 8, i3 = i + 12;
        int c0 = col[i];
        int c1 = col[i1 < e ? i1 : e - 1];
        int c2 = col[i2 < e ? i2 : e - 1];
        int c3 = col[i3 < e ? i3 : e - 1];
        float f1 = (i1 < e) ? 1.f : 0.f;
        float f2 = (i2 < e) ? 1.f : 0.f;
        float f3 = (i3 < e) ? 1.f : 0.f;
        float4 g0 = *(const float4*)(G + (size_t)c0 * D + fg4);
        float4 g1 = *(const float4*)(G + (size_t)c1 * D + fg4);
        float4 g2 = *(const float4*)(G + (size_t)c2 * D + fg4);
        float4 g3 = *(const float4*)(G + (size_t)c3 * D + fg4);
        acc.x += g0.x; acc.y += g0.y; acc.z += g0.z; acc.w += g0.w;
        acc.x = fmaf(f1, g1.x, acc.x); acc.y = fmaf(f1, g1.y, acc.y);
        acc.z = fmaf(f1, g1.z, acc.z); acc.w = fmaf(f1, g1.w, acc.w);
        acc.x = fmaf(f2, g2.x, acc.x); acc.y = fmaf(f2, g2.y, acc.y);
        acc.z = fmaf(f2, g2.z, acc.z); acc.w = fmaf(f2, g2.w, acc.w);
        acc.x = fmaf(f3, g3.x, acc.x); acc.y = fmaf(f3, g3.y, acc.y);
        acc.z = fmaf(f3, g3.z, acc.z); acc.w = fmaf(f3, g3.w, acc.w);
    }

    #pragma unroll
    for (int m = 16; m < 64; m <<= 1) {
        acc.x += __shfl_xor(acc.x, m, 64);
        acc.y += __shfl_xor(acc.y, m, 64);
        acc.z += __shfl_xor(acc.z, m, 64);
        acc.w += __shfl_xor(acc.w, m, 64);
    }

    float4 self = *(const float4*)(G + (size_t)n * D + fg4);
    float4 bv   = *(const float4*)(bias + fg4);
    float dsc = dis[n];
    float4 o;
    o.x = fmaf(dsc, acc.x + self.x, bv.x);
    o.y = fmaf(dsc, acc.y + self.y, bv.y);
    o.z = fmaf(dsc, acc.z + self.z, bv.z);
    o.w = fmaf(dsc, acc.w + self.w, bv.w);
    if (es == 0) *(float4*)(Out + (size_t)n * D + fg4) = o;
}

// ---------- pooling ----------

__global__ void k_bounds(const int* __restrict__ batch, int* __restrict__ start) {
    int g = blockIdx.x * blockDim.x + threadIdx.x;
    if (g <= N_GRAPHS) {
        int lo = 0, hi = N_NODES;
        while (lo < hi) {
            int mid = (lo + hi) >> 1;
            if (batch[mid] < g) lo = mid + 1; else hi = mid;
        }
        start[g] = lo;
    }
}

__global__ __launch_bounds__(256) void k_pool(
        const float* __restrict__ H, const int* __restrict__ start,
        float* __restrict__ P) {
    int g = blockIdx.x * 4 + (threadIdx.x >> 6);
    if (g >= N_GRAPHS) return;
    int lane = threadIdx.x & 63;
    int es  = lane >> 4;
    int fg4 = (lane & 15) * 4;
    int s = start[g], e = start[g + 1];
    float4 acc = {0.f, 0.f, 0.f, 0.f};
    for (int r = s + es; r < e; r += 4) {
        float4 h = *(const float4*)(H + (size_t)r * D + fg4);
        acc.x += h.x; acc.y += h.y; acc.z += h.z; acc.w += h.w;
    }
    #pragma unroll
    for (int m = 16; m < 64; m <<= 1) {
        acc.x += __shfl_xor(acc.x, m, 64);
        acc.y += __shfl_xor(acc.y, m, 64);
        acc.z += __shfl_xor(acc.z, m, 64);
        acc.w += __shfl_xor(acc.w, m, 64);
    }
    int cntr = e - s;
    float inv = 1.0f / (float)(cntr > 0 ? cntr : 1);
    if (es == 0) {
        float4 o;
        o.x = acc.x * inv; o.y = acc.y * inv; o.z = acc.z * inv; o.w = acc.w * inv;
        *(float4*)(P + g * D + fg4) = o;
    }
}

// ---------- classifier MLP ----------

__global__ __launch_bounds__(128) void k_mlp(
        const float* __restrict__ P,
        const float* __restrict__ w1, const float* __restrict__ b1,
        const float* __restrict__ w2, const float* __restrict__ b2,
        const float* __restrict__ fcw, const float* __restrict__ fcb,
        float* __restrict__ out) {
    __shared__ float ps[64];
    __shared__ float red[128];
    int g = blockIdx.x, t = threadIdx.x;
    if (t < 64) ps[t] = P[g * D + t];
    __syncthreads();
    float acc = b1[t];
    #pragma unroll
    for (int k = 0; k < 64; k++) acc = fmaf(ps[k], w1[k * D_CLS + t], acc);
    red[t] = acc * w2[t];
    __syncthreads();
    for (int s2 = 64; s2 > 0; s2 >>= 1) {
        if (t < s2) red[t] += red[t + s2];
        __syncthreads();
    }
    if (t == 0) {
        float o = red[0] + b2[0];
        o = fmaf(o, fcw[0], fcb[0]);
        out[g] = (o >= 0.f) ? o : 0.01f * o;
    }
}

// ---------- launch ----------

extern "C" void kernel_launch(void* const* d_in, const int* in_sizes, int n_in,
                              void* d_out, int out_size, void* d_ws, size_t ws_size,
                              hipStream_t stream) {
    const float* x   = (const float*)d_in[0];
    const float* W0  = (const float*)d_in[1];
    const float* b0  = (const float*)d_in[2];
    const float* W1  = (const float*)d_in[3];
    const float* b1  = (const float*)d_in[4];
    const float* W2  = (const float*)d_in[5];
    const float* b2  = (const float*)d_in[6];
    const float* l1w = (const float*)d_in[7];
    const float* l1b = (const float*)d_in[8];
    const float* l2w = (const float*)d_in[9];
    const float* l2b = (const float*)d_in[10];
    const float* fcw = (const float*)d_in[11];
    const float* fcb = (const float*)d_in[12];
    const int* eidx  = (const int*)d_in[13];
    const int* batch = (const int*)d_in[14];
    const int* src = eidx;
    const int* dst = eidx + N_EDGES;

    char* ws = (char*)d_ws;
    size_t off = 0;
    auto alloc = [&](size_t bytes) -> void* {
        off = (off + 255) & ~(size_t)255;
        void* p = ws + off;
        off += bytes;
        return p;
    };

    int*   row_ptr = (int*)  alloc((N_NODES + 1) * sizeof(int));
    int*   cnt     = (int*)  alloc(N_NODES * sizeof(int));
    int*   bsum    = (int*)  alloc(256 * sizeof(int));
    int*   btail   = (int*)  alloc(NBUK * sizeof(int));
    int*   ebuf    = (int*)  alloc(N_EDGES * sizeof(int));
    int*   col     = (int*)  alloc(N_EDGES * sizeof(int));
    float* dis     = (float*)alloc(N_NODES * sizeof(float));
    int*   start   = (int*)  alloc((N_GRAPHS + 1) * sizeof(int));
    float* bufA    = (float*)alloc((size_t)N_NODES * D * sizeof(float));
    float* bufB    = (float*)alloc((size_t)N_NODES * D * sizeof(float));
    float* bufC    = (float*)alloc((size_t)N_NODES * D * sizeof(float));
    float* pooled  = (float*)alloc((size_t)N_GRAPHS * D * sizeof(float));

    const int nbScan = cdiv(N_NODES, 256);   // 196
    const int nbE    = cdiv(N_EDGES, 256);   // 3125

    hipMemsetAsync(cnt, 0, N_NODES * sizeof(int), stream);

    k_hist<<<nbE, 256, 0, stream>>>(dst, cnt);
    k_dis<<<nbScan, 256, 0, stream>>>(cnt, dis);
    k_scan1<<<nbScan, 256, 0, stream>>>(cnt, bsum);
    k_scan2<<<1, 256, 0, stream>>>(bsum, nbScan);
    k_scan3<<<nbScan, 256, 0, stream>>>(cnt, bsum, row_ptr);
    k_binit<<<cdiv(NBUK, 256), 256, 0, stream>>>(row_ptr, btail);
    k_part<<<cdiv(N_EDGES, PART_TILE), 256, 0, stream>>>(src, dst, btail, ebuf);
    k_place<<<NBUK, 256, 0, stream>>>(ebuf, row_ptr, cnt, col);

    const int nbGemm = cdiv(N_NODES, 64);    // 782
    const int nbAgg  = cdiv(N_NODES, 4);     // 12500

    // layer 0: x -> B
    k_gemm_scale<<<nbGemm, 256, 0, stream>>>(x, W0, dis, bufA);
    k_agg<<<nbAgg, 256, 0, stream>>>(bufA, row_ptr, col, dis, b0, bufB);
    // layer 1: B -> C
    k_gemm_scale<<<nbGemm, 256, 0, stream>>>(bufB, W1, dis, bufA);
    k_agg<<<nbAgg, 256, 0, stream>>>(bufA, row_ptr, col, dis, b1, bufC);
    // layer 2: C -> B
    k_gemm_scale<<<nbGemm, 256, 0, stream>>>(bufC, W2, dis, bufA);
    k_agg<<<nbAgg, 256, 0, stream>>>(bufA, row_ptr, col, dis, b2, bufB);

    k_bounds<<<cdiv(N_GRAPHS + 1, 256), 256, 0, stream>>>(batch, start);
    k_pool<<<cdiv(N_GRAPHS, 4), 256, 0, stream>>>(bufB, start, pooled);
    k_mlp<<<N_GRAPHS, 128, 0, stream>>>(pooled, l1w, l1b, l2w, l2b, fcw, fcb,
                                        (float*)d_out);
}

// Round 6
// 235.416 us; speedup vs baseline: 5.0486x; 1.0134x over previous
//
#include <hip/hip_runtime.h>
#include <math.h>

#define N_NODES 50000
#define N_EDGES 800000
#define N_GRAPHS 512
#define D 64
#define D_CLS 128
#define BNODES 128                       // dst nodes per bucket
#define NBUK 391                         // cdiv(N_NODES, BNODES)
#define PART_TILE 4096                   // edges per k_part block (256 thr x 16)

static inline int cdiv(int a, int b) { return (a + b - 1) / b; }

// ---------- zero (replaces hipMemsetAsync; keeps graph clean) ----------

__global__ void k_zero(int* __restrict__ p, int nwords) {
    int i = blockIdx.x * blockDim.x + threadIdx.x;
    if (i < nwords) p[i] = 0;
}

// ---------- degree histogram (per node) ----------

__global__ void k_hist(const int* __restrict__ dst, int* __restrict__ cnt) {
    int e = blockIdx.x * blockDim.x + threadIdx.x;
    if (e < N_EDGES) atomicAdd(&cnt[dst[e]], 1);
}

__global__ void k_dis(const int* __restrict__ cnt, float* __restrict__ dis) {
    int i = blockIdx.x * blockDim.x + threadIdx.x;
    if (i < N_NODES) dis[i] = 1.0f / sqrtf((float)cnt[i] + 1.0f);
}

// ---------- row_ptr scan (196 blocks of 256) ----------

__global__ void k_scan1(const int* __restrict__ cnt, int* __restrict__ bsum) {
    __shared__ int s[256];
    int i = blockIdx.x * 256 + threadIdx.x;
    s[threadIdx.x] = (i < N_NODES) ? cnt[i] : 0;
    __syncthreads();
    for (int off = 128; off > 0; off >>= 1) {
        if (threadIdx.x < off) s[threadIdx.x] += s[threadIdx.x + off];
        __syncthreads();
    }
    if (threadIdx.x == 0) bsum[blockIdx.x] = s[0];
}

__global__ void k_scan2(int* bsum, int nb) {
    __shared__ int s[256];
    int t = threadIdx.x;
    int v = (t < nb) ? bsum[t] : 0;
    s[t] = v;
    __syncthreads();
    for (int off = 1; off < 256; off <<= 1) {
        int x = (t >= off) ? s[t - off] : 0;
        __syncthreads();
        s[t] += x;
        __syncthreads();
    }
    if (t < nb) bsum[t] = s[t] - v;
}

__global__ void k_scan3(const int* __restrict__ cnt, const int* __restrict__ bsum,
                        int* __restrict__ row_ptr) {
    __shared__ int s[256];
    int i = blockIdx.x * 256 + threadIdx.x;
    int v = (i < N_NODES) ? cnt[i] : 0;
    s[threadIdx.x] = v;
    __syncthreads();
    for (int off = 1; off < 256; off <<= 1) {
        int x = (threadIdx.x >= off) ? s[threadIdx.x - off] : 0;
        __syncthreads();
        s[threadIdx.x] += x;
        __syncthreads();
    }
    if (i < N_NODES) row_ptr[i] = bsum[blockIdx.x] + s[threadIdx.x] - v;
    if (i == 0) row_ptr[N_NODES] = N_EDGES;
}

__global__ void k_binit(const int* __restrict__ row_ptr, int* __restrict__ btail) {
    int b = blockIdx.x * blockDim.x + threadIdx.x;
    if (b < NBUK) btail[b] = row_ptr[b * BNODES];
}

// ---------- partition edges into buckets (LDS histogram, 1 atomic/(blk,buk)) ----

__global__ __launch_bounds__(256) void k_part(
        const int* __restrict__ src, const int* __restrict__ dst,
        int* __restrict__ btail, int* __restrict__ ebuf) {
    __shared__ int lcnt[NBUK];
    __shared__ int lbase[NBUK];
    int t = threadIdx.x;
    for (int i = t; i < NBUK; i += 256) lcnt[i] = 0;
    __syncthreads();

    int e0 = blockIdx.x * PART_TILE + t;
    int ent[16];
    int br[16];
    #pragma unroll
    for (int k = 0; k < 16; k++) {
        int e = e0 + k * 256;
        if (e < N_EDGES) {
            int d = dst[e];
            int b = d / BNODES;
            int r = atomicAdd(&lcnt[b], 1);
            ent[k] = src[e] | ((d & (BNODES - 1)) << 16);  // src(16b)|dlocal(7b)
            br[k] = (b << 16) | r;                          // r < 4096
        } else {
            br[k] = -1;
        }
    }
    __syncthreads();
    for (int i = t; i < NBUK; i += 256) {
        int c = lcnt[i];
        lbase[i] = c ? atomicAdd(&btail[i], c) : 0;
    }
    __syncthreads();
    #pragma unroll
    for (int k = 0; k < 16; k++) {
        if (br[k] >= 0) {
            int b = br[k] >> 16, r = br[k] & 0xFFFF;
            ebuf[lbase[b] + r] = ent[k];
        }
    }
}

// ---------- exact CSR placement; writes confined to ~8KB bucket region ----------

__global__ __launch_bounds__(256) void k_place(
        const int* __restrict__ ebuf, const int* __restrict__ row_ptr,
        int* __restrict__ cnt, int* __restrict__ col) {
    int b = blockIdx.x;
    int n0 = b * BNODES;
    int nhi = n0 + BNODES;
    if (nhi > N_NODES) nhi = N_NODES;
    int s = row_ptr[n0];
    int e = row_ptr[nhi];
    for (int i = s + threadIdx.x; i < e; i += 256) {
        int v = ebuf[i];
        int d = n0 | (v >> 16);
        int pos = row_ptr[d] + atomicSub(&cnt[d], 1) - 1;
        col[pos] = v & 0xFFFF;
    }
}

// ---------- GEMM (X @ W) with dis-row-scaling fused: G = dis ⊙ (X @ W) ----------

#define XS_STRIDE 68   // 64 + 4 pad, keeps 16B alignment for float4 LDS ops

__global__ __launch_bounds__(256) void k_gemm_scale(
        const float* __restrict__ X, const float* __restrict__ W,
        const float* __restrict__ dis, float* __restrict__ G) {
    __shared__ float Xs[64 * XS_STRIDE];
    __shared__ float Ws[64 * 64];
    int n0 = blockIdx.x * 64;
    int t = threadIdx.x;

    {
        int base = t * 16;
        const float4* wsrc = (const float4*)(W + base);
        float4* wdst = (float4*)(Ws + base);
        wdst[0] = wsrc[0]; wdst[1] = wsrc[1]; wdst[2] = wsrc[2]; wdst[3] = wsrc[3];
    }
    {
        int row = t >> 2;
        int c0 = (t & 3) * 16;
        int grow = n0 + row;
        float4* xd = (float4*)(Xs + row * XS_STRIDE + c0);
        if (grow < N_NODES) {
            const float4* xp = (const float4*)(X + (size_t)grow * D + c0);
            xd[0] = xp[0]; xd[1] = xp[1]; xd[2] = xp[2]; xd[3] = xp[3];
        } else {
            float4 z = {0.f, 0.f, 0.f, 0.f};
            xd[0] = z; xd[1] = z; xd[2] = z; xd[3] = z;
        }
    }
    __syncthreads();

    int tc = t & 15, tr = t >> 4;
    int r0 = tr * 4, c0 = tc * 4;
    float acc[4][4] = {};
    #pragma unroll 4
    for (int k = 0; k < 64; k++) {
        float4 wv = *(const float4*)&Ws[k * 64 + c0];
        #pragma unroll
        for (int i = 0; i < 4; i++) {
            float xv = Xs[(r0 + i) * XS_STRIDE + k];
            acc[i][0] = fmaf(xv, wv.x, acc[i][0]);
            acc[i][1] = fmaf(xv, wv.y, acc[i][1]);
            acc[i][2] = fmaf(xv, wv.z, acc[i][2]);
            acc[i][3] = fmaf(xv, wv.w, acc[i][3]);
        }
    }
    #pragma unroll
    for (int i = 0; i < 4; i++) {
        int grow = n0 + r0 + i;
        if (grow < N_NODES) {
            float dsc = dis[grow];
            float4 o;
            o.x = acc[i][0] * dsc; o.y = acc[i][1] * dsc;
            o.z = acc[i][2] * dsc; o.w = acc[i][3] * dsc;
            *(float4*)&G[(size_t)grow * D + c0] = o;
        }
    }
}

// ---------- aggregation: Out_n = dis_n * (G_n + sum_{src in in(n)} G_src) + b ----
// 16-lane group per node (lane owns one float4 of the row). 8-deep predicated
// edge walk -> 8 gathers in flight per lane, 32 per wave. No shuffles.

__global__ __launch_bounds__(256) void k_agg(
        const float* __restrict__ G, const int* __restrict__ row_ptr,
        const int* __restrict__ col, const float* __restrict__ dis,
        const float* __restrict__ bias, float* __restrict__ Out) {
    int t = threadIdx.x;
    int grp = t >> 4;                 // 16 node-groups per block
    int fl4 = (t & 15) * 4;           // feature float4 offset
    int n = blockIdx.x * 16 + grp;    // grid = 3125 -> n < 50000 always

    int s = row_ptr[n], e = row_ptr[n + 1];
    float4 acc = *(const float4*)(G + (size_t)n * D + fl4);   // self term

    for (int i = s; i < e; i += 8) {
        int i1 = i + 1, i2 = i + 2, i3 = i + 3;
        int i4 = i + 4, i5 = i + 5, i6 = i + 6, i7 = i + 7;
        int c0 = col[i];
        int c1 = col[i1 < e ? i1 : i];
        int c2 = col[i2 < e ? i2 : i];
        int c3 = col[i3 < e ? i3 : i];
        int c4 = col[i4 < e ? i4 : i];
        int c5 = col[i5 < e ? i5 : i];
        int c6 = col[i6 < e ? i6 : i];
        int c7 = col[i7 < e ? i7 : i];
        float f1 = (i1 < e) ? 1.f : 0.f;
        float f2 = (i2 < e) ? 1.f : 0.f;
        float f3 = (i3 < e) ? 1.f : 0.f;
        float f4 = (i4 < e) ? 1.f : 0.f;
        float f5 = (i5 < e) ? 1.f : 0.f;
        float f6 = (i6 < e) ? 1.f : 0.f;
        float f7 = (i7 < e) ? 1.f : 0.f;
        float4 g0 = *(const float4*)(G + (size_t)c0 * D + fl4);
        float4 g1 = *(const float4*)(G + (size_t)c1 * D + fl4);
        float4 g2 = *(const float4*)(G + (size_t)c2 * D + fl4);
        float4 g3 = *(const float4*)(G + (size_t)c3 * D + fl4);
        float4 g4 = *(const float4*)(G + (size_t)c4 * D + fl4);
        float4 g5 = *(const float4*)(G + (size_t)c5 * D + fl4);
        float4 g6 = *(const float4*)(G + (size_t)c6 * D + fl4);
        float4 g7 = *(const float4*)(G + (size_t)c7 * D + fl4);
        acc.x += g0.x; acc.y += g0.y; acc.z += g0.z; acc.w += g0.w;
        acc.x = fmaf(f1, g1.x, acc.x); acc.y = fmaf(f1, g1.y, acc.y);
        acc.z = fmaf(f1, g1.z, acc.z); acc.w = fmaf(f1, g1.w, acc.w);
        acc.x = fmaf(f2, g2.x, acc.x); acc.y = fmaf(f2, g2.y, acc.y);
        acc.z = fmaf(f2, g2.z, acc.z); acc.w = fmaf(f2, g2.w, acc.w);
        acc.x = fmaf(f3, g3.x, acc.x); acc.y = fmaf(f3, g3.y, acc.y);
        acc.z = fmaf(f3, g3.z, acc.z); acc.w = fmaf(f3, g3.w, acc.w);
        acc.x = fmaf(f4, g4.x, acc.x); acc.y = fmaf(f4, g4.y, acc.y);
        acc.z = fmaf(f4, g4.z, acc.z); acc.w = fmaf(f4, g4.w, acc.w);
        acc.x = fmaf(f5, g5.x, acc.x); acc.y = fmaf(f5, g5.y, acc.y);
        acc.z = fmaf(f5, g5.z, acc.z); acc.w = fmaf(f5, g5.w, acc.w);
        acc.x = fmaf(f6, g6.x, acc.x); acc.y = fmaf(f6, g6.y, acc.y);
        acc.z = fmaf(f6, g6.z, acc.z); acc.w = fmaf(f6, g6.w, acc.w);
        acc.x = fmaf(f7, g7.x, acc.x); acc.y = fmaf(f7, g7.y, acc.y);
        acc.z = fmaf(f7, g7.z, acc.z); acc.w = fmaf(f7, g7.w, acc.w);
    }

    float dsc = dis[n];
    float4 bv = *(const float4*)(bias + fl4);
    float4 o;
    o.x = fmaf(dsc, acc.x, bv.x);
    o.y = fmaf(dsc, acc.y, bv.y);
    o.z = fmaf(dsc, acc.z, bv.z);
    o.w = fmaf(dsc, acc.w, bv.w);
    *(float4*)(Out + (size_t)n * D + fl4) = o;
}

// ---------- pooling ----------

__global__ void k_bounds(const int* __restrict__ batch, int* __restrict__ start) {
    int g = blockIdx.x * blockDim.x + threadIdx.x;
    if (g <= N_GRAPHS) {
        int lo = 0, hi = N_NODES;
        while (lo < hi) {
            int mid = (lo + hi) >> 1;
            if (batch[mid] < g) lo = mid + 1; else hi = mid;
        }
        start[g] = lo;
    }
}

__global__ __launch_bounds__(256) void k_pool(
        const float* __restrict__ H, const int* __restrict__ start,
        float* __restrict__ P) {
    int g = blockIdx.x * 4 + (threadIdx.x >> 6);
    if (g >= N_GRAPHS) return;
    int lane = threadIdx.x & 63;
    int es  = lane >> 4;
    int fg4 = (lane & 15) * 4;
    int s = start[g], e = start[g + 1];
    float4 acc = {0.f, 0.f, 0.f, 0.f};
    for (int r = s + es; r < e; r += 4) {
        float4 h = *(const float4*)(H + (size_t)r * D + fg4);
        acc.x += h.x; acc.y += h.y; acc.z += h.z; acc.w += h.w;
    }
    #pragma unroll
    for (int m = 16; m < 64; m <<= 1) {
        acc.x += __shfl_xor(acc.x, m, 64);
        acc.y += __shfl_xor(acc.y, m, 64);
        acc.z += __shfl_xor(acc.z, m, 64);
        acc.w += __shfl_xor(acc.w, m, 64);
    }
    int cntr = e - s;
    float inv = 1.0f / (float)(cntr > 0 ? cntr : 1);
    if (es == 0) {
        float4 o;
        o.x = acc.x * inv; o.y = acc.y * inv; o.z = acc.z * inv; o.w = acc.w * inv;
        *(float4*)(P + g * D + fg4) = o;
    }
}

// ---------- classifier MLP ----------

__global__ __launch_bounds__(128) void k_mlp(
        const float* __restrict__ P,
        const float* __restrict__ w1, const float* __restrict__ b1,
        const float* __restrict__ w2, const float* __restrict__ b2,
        const float* __restrict__ fcw, const float* __restrict__ fcb,
        float* __restrict__ out) {
    __shared__ float ps[64];
    __shared__ float red[128];
    int g = blockIdx.x, t = threadIdx.x;
    if (t < 64) ps[t] = P[g * D + t];
    __syncthreads();
    float acc = b1[t];
    #pragma unroll
    for (int k = 0; k < 64; k++) acc = fmaf(ps[k], w1[k * D_CLS + t], acc);
    red[t] = acc * w2[t];
    __syncthreads();
    for (int s2 = 64; s2 > 0; s2 >>= 1) {
        if (t < s2) red[t] += red[t + s2];
        __syncthreads();
    }
    if (t == 0) {
        float o = red[0] + b2[0];
        o = fmaf(o, fcw[0], fcb[0]);
        out[g] = (o >= 0.f) ? o : 0.01f * o;
    }
}

// ---------- launch ----------

extern "C" void kernel_launch(void* const* d_in, const int* in_sizes, int n_in,
                              void* d_out, int out_size, void* d_ws, size_t ws_size,
                              hipStream_t stream) {
    const float* x   = (const float*)d_in[0];
    const float* W0  = (const float*)d_in[1];
    const float* b0  = (const float*)d_in[2];
    const float* W1  = (const float*)d_in[3];
    const float* b1  = (const float*)d_in[4];
    const float* W2  = (const float*)d_in[5];
    const float* b2  = (const float*)d_in[6];
    const float* l1w = (const float*)d_in[7];
    const float* l1b = (const float*)d_in[8];
    const float* l2w = (const float*)d_in[9];
    const float* l2b = (const float*)d_in[10];
    const float* fcw = (const float*)d_in[11];
    const float* fcb = (const float*)d_in[12];
    const int* eidx  = (const int*)d_in[13];
    const int* batch = (const int*)d_in[14];
    const int* src = eidx;
    const int* dst = eidx + N_EDGES;

    char* ws = (char*)d_ws;
    size_t off = 0;
    auto alloc = [&](size_t bytes) -> void* {
        off = (off + 255) & ~(size_t)255;
        void* p = ws + off;
        off += bytes;
        return p;
    };

    int*   row_ptr = (int*)  alloc((N_NODES + 1) * sizeof(int));
    int*   cnt     = (int*)  alloc(N_NODES * sizeof(int));
    int*   bsum    = (int*)  alloc(256 * sizeof(int));
    int*   btail   = (int*)  alloc(NBUK * sizeof(int));
    int*   ebuf    = (int*)  alloc(N_EDGES * sizeof(int));
    int*   col     = (int*)  alloc(N_EDGES * sizeof(int));
    float* dis     = (float*)alloc(N_NODES * sizeof(float));
    int*   start   = (int*)  alloc((N_GRAPHS + 1) * sizeof(int));
    float* bufA    = (float*)alloc((size_t)N_NODES * D * sizeof(float));
    float* bufB    = (float*)alloc((size_t)N_NODES * D * sizeof(float));
    float* bufC    = (float*)alloc((size_t)N_NODES * D * sizeof(float));
    float* pooled  = (float*)alloc((size_t)N_GRAPHS * D * sizeof(float));

    const int nbScan = cdiv(N_NODES, 256);   // 196
    const int nbE    = cdiv(N_EDGES, 256);   // 3125

    k_zero<<<nbScan, 256, 0, stream>>>(cnt, N_NODES);
    k_hist<<<nbE, 256, 0, stream>>>(dst, cnt);
    k_dis<<<nbScan, 256, 0, stream>>>(cnt, dis);
    k_scan1<<<nbScan, 256, 0, stream>>>(cnt, bsum);
    k_scan2<<<1, 256, 0, stream>>>(bsum, nbScan);
    k_scan3<<<nbScan, 256, 0, stream>>>(cnt, bsum, row_ptr);
    k_binit<<<cdiv(NBUK, 256), 256, 0, stream>>>(row_ptr, btail);
    k_part<<<cdiv(N_EDGES, PART_TILE), 256, 0, stream>>>(src, dst, btail, ebuf);
    k_place<<<NBUK, 256, 0, stream>>>(ebuf, row_ptr, cnt, col);

    const int nbGemm = cdiv(N_NODES, 64);    // 782
    const int nbAgg  = cdiv(N_NODES, 16);    // 3125

    // layer 0: x -> B
    k_gemm_scale<<<nbGemm, 256, 0, stream>>>(x, W0, dis, bufA);
    k_agg<<<nbAgg, 256, 0, stream>>>(bufA, row_ptr, col, dis, b0, bufB);
    // layer 1: B -> C
    k_gemm_scale<<<nbGemm, 256, 0, stream>>>(bufB, W1, dis, bufA);
    k_agg<<<nbAgg, 256, 0, stream>>>(bufA, row_ptr, col, dis, b1, bufC);
    // layer 2: C -> B
    k_gemm_scale<<<nbGemm, 256, 0, stream>>>(bufC, W2, dis, bufA);
    k_agg<<<nbAgg, 256, 0, stream>>>(bufA, row_ptr, col, dis, b2, bufB);

    k_bounds<<<cdiv(N_GRAPHS + 1, 256), 256, 0, stream>>>(batch, start);
    k_pool<<<cdiv(N_GRAPHS, 4), 256, 0, stream>>>(bufB, start, pooled);
    k_mlp<<<N_GRAPHS, 128, 0, stream>>>(pooled, l1w, l1b, l2w, l2b, fcw, fcb,
                                        (float*)d_out);
}